// Round 10
// baseline (86.994 us; speedup 1.0000x reference)
//
#include <hip/hip_runtime.h>

typedef float f32x4 __attribute__((ext_vector_type(4)));
typedef short s16x4 __attribute__((ext_vector_type(4)));
typedef short s16x8 __attribute__((ext_vector_type(8)));

#define LOG2E 1.4426950408889634f

// ---- bf16 helpers (bit-level, RNE) ----
__device__ __forceinline__ short f2bf(float f) {
  unsigned u = __float_as_uint(f);
  unsigned r = (u + 0x7fffu + ((u >> 16) & 1u)) >> 16;
  return (short)r;
}
__device__ __forceinline__ float bf2f(short s) {
  return __uint_as_float(((unsigned)(unsigned short)s) << 16);
}
// packed f32->bf16 (RNE), 2 elems/inst. D[15:0]=cvt(a), D[31:16]=cvt(b).
__device__ __forceinline__ unsigned cvt_pk_bf16(float a, float b) {
  unsigned r;
  asm("v_cvt_pk_bf16_f32 %0, %1, %2" : "=v"(r) : "v"(a), "v"(b));
  return r;
}

// 16x16x16 bf16. D: col(lane&15)=B-idx, row(4g+reg)=A-idx  [HW-verified]
__device__ __forceinline__ f32x4 mfma16(s16x4 a, s16x4 b, f32x4 c) {
  return __builtin_amdgcn_mfma_f32_16x16x16bf16_1k(a, b, c, 0, 0, 0);
}
// 16x16x32 bf16 (gfx950). Same C/D layout. kappa-matched A/B (g,e)->g*8+e.
__device__ __forceinline__ f32x4 mfma32(s16x8 a, s16x8 b, f32x4 c) {
  return __builtin_amdgcn_mfma_f32_16x16x32_bf16(a, b, c, 0, 0, 0);
}

// async global->LDS, 16B/lane: HW writes lane i at (uniform dst)+i*16.
__device__ __forceinline__ void gl_lds16(const void* gp, void* sp) {
  __builtin_amdgcn_global_load_lds(
      (__attribute__((address_space(1))) void*)const_cast<void*>(gp),
      (__attribute__((address_space(3))) void*)sp, 16, 0, 0);
}

// ============================================================
// Kernel 0: split W^T into bf16 hi/lo (UNCHANGED).
// ============================================================
__global__ __launch_bounds__(256) void prep_w(
    const float* __restrict__ Wq, const float* __restrict__ Wk, const float* __restrict__ Wv,
    short* __restrict__ wt_hi, short* __restrict__ wt_lo) {
  int idx = blockIdx.x * 256 + threadIdx.x;   // 192*1024 total
  int n = idx >> 10;
  int c = idx & 1023;
  const float* W = (n < 64) ? Wq : ((n < 128) ? Wk : Wv);
  float v = W[c * 64 + (n & 63)];
  short hi = f2bf(v);
  short lo = f2bf(v - bf2f(hi));
  wt_hi[idx] = hi;
  wt_lo[idx] = lo;
}

// ============================================================
// Kernel 1: QKV projection — BK=32, 5-buffer distance-4 gl_lds pipeline
// (UNCHANGED from R6-R9 — vmcnt counting valid: no spills, only gl_lds).
// ============================================================
__global__ __launch_bounds__(512, 2) void proj_qkv(
    const float* __restrict__ x,
    const short* __restrict__ wt_hi, const short* __restrict__ wt_lo,
    const float* __restrict__ bq, const float* __restrict__ bk, const float* __restrict__ bv,
    short* __restrict__ q_hi, short* __restrict__ q_lo,
    short* __restrict__ k_hi, short* __restrict__ k_lo,
    short* __restrict__ v_t) {
  const int tid = threadIdx.x;
  const int lane = tid & 63;
  const int wv = tid >> 6;       // 0..7
  const int col = lane & 15;
  const int g = lane >> 4;       // 0..3
  const int mg = wv >> 2;        // 0..1
  const int ng = wv & 3;         // 0..3
  const int tokbase = blockIdx.x * 32;

  __shared__ short lds[5][12288];   // 5 x 24KB = 120KB

  const int wsl = ((lane & 3) ^ ((lane >> 3) & 3)) * 8;   // W src slot (shorts)
  const short* s0 = wt_hi + (size_t)(16 * wv + (lane >> 2)) * 1024 + wsl;
  const int d0 = wv * 512;
  const int c1 = wv + 8;
  const short* s1 = (c1 < 12 ? wt_hi + (size_t)(16 * c1 + (lane >> 2)) * 1024
                             : wt_lo + (size_t)(16 * (c1 - 12) + (lane >> 2)) * 1024) + wsl;
  const int d1 = (c1 < 12) ? c1 * 512 : 6144 + (c1 - 12) * 512;
  const int c2 = wv + 16;
  const bool isx = (c2 >= 20);
  const short* s2 = isx
      ? (const short*)(x + (size_t)(tokbase + 8 * (c2 - 20) + (lane >> 3)) * 1024 +
                       ((lane & 7) ^ (lane >> 3)) * 4)
      : wt_lo + (size_t)(16 * (c2 - 12) + (lane >> 2)) * 1024 + wsl;
  const int d2 = isx ? 10240 + (c2 - 20) * 512 : 6144 + (c2 - 12) * 512;
  const int st2 = isx ? 64 : 32;   // per-step src advance in shorts

#define STAGE(BP, S) do { \
    gl_lds16(s0 + (S) * 32, (BP) + d0); \
    gl_lds16(s1 + (S) * 32, (BP) + d1); \
    gl_lds16(s2 + (S) * st2, (BP) + d2); \
  } while (0)

#define PIPE_WAIT(N) do { \
    asm volatile("s_waitcnt vmcnt(" #N ")" ::: "memory"); \
    __builtin_amdgcn_s_barrier(); \
    __builtin_amdgcn_sched_barrier(0); \
  } while (0)
#define PIPE_END do { \
    asm volatile("s_waitcnt lgkmcnt(0)" ::: "memory"); \
    __builtin_amdgcn_sched_barrier(0); \
    __builtin_amdgcn_s_barrier(); \
  } while (0)

  const int arow = mg * 16 + col;                 // x row
  const int xq0 = ((2 * g) ^ (arow & 7)) << 2;    // f32 offsets within x row
  const int xq1 = ((2 * g + 1) ^ (arow & 7)) << 2;
  const int rq = ng * 16 + col;                   // W row (q); k:+64, v:+128
  const int ws = (g ^ ((rq >> 1) & 3)) << 3;      // W slot (shorts)

  f32x4 accQ = {0,0,0,0}, accK = {0,0,0,0}, accV = {0,0,0,0};

  typedef union { unsigned u[4]; s16x8 v8; } pk8;

#define COMPUTE(BP) do { \
    const short* bp_ = (BP); \
    const float* xb_ = (const float*)(bp_ + 10240); \
    f32x4 x0_ = *(const f32x4*)(xb_ + arow * 32 + xq0); \
    f32x4 x1_ = *(const f32x4*)(xb_ + arow * 32 + xq1); \
    pk8 xh_, xl_; \
    xh_.u[0] = cvt_pk_bf16(x0_[0], x0_[1]); \
    xh_.u[1] = cvt_pk_bf16(x0_[2], x0_[3]); \
    xh_.u[2] = cvt_pk_bf16(x1_[0], x1_[1]); \
    xh_.u[3] = cvt_pk_bf16(x1_[2], x1_[3]); \
    xl_.u[0] = cvt_pk_bf16(x0_[0] - __uint_as_float(xh_.u[0] << 16), \
                           x0_[1] - __uint_as_float(xh_.u[0] & 0xffff0000u)); \
    xl_.u[1] = cvt_pk_bf16(x0_[2] - __uint_as_float(xh_.u[1] << 16), \
                           x0_[3] - __uint_as_float(xh_.u[1] & 0xffff0000u)); \
    xl_.u[2] = cvt_pk_bf16(x1_[0] - __uint_as_float(xh_.u[2] << 16), \
                           x1_[1] - __uint_as_float(xh_.u[2] & 0xffff0000u)); \
    xl_.u[3] = cvt_pk_bf16(x1_[2] - __uint_as_float(xh_.u[3] << 16), \
                           x1_[3] - __uint_as_float(xh_.u[3] & 0xffff0000u)); \
    s16x8 qh_ = *(const s16x8*)(bp_ + rq * 32 + ws); \
    s16x8 kh_ = *(const s16x8*)(bp_ + (64 + rq) * 32 + ws); \
    s16x8 vh_ = *(const s16x8*)(bp_ + (128 + rq) * 32 + ws); \
    s16x8 ql_ = *(const s16x8*)(bp_ + 6144 + rq * 32 + ws); \
    s16x8 kl_ = *(const s16x8*)(bp_ + 6144 + (64 + rq) * 32 + ws); \
    accQ = mfma32(xh_.v8, qh_, accQ); \
    accK = mfma32(xh_.v8, kh_, accK); \
    accV = mfma32(xh_.v8, vh_, accV); \
    accQ = mfma32(xl_.v8, qh_, accQ); \
    accK = mfma32(xl_.v8, kh_, accK); \
    accQ = mfma32(xh_.v8, ql_, accQ); \
    accK = mfma32(xh_.v8, kl_, accK); \
  } while (0)

  short* cA = &lds[0][0];
  short* cB = &lds[1][0];
  short* cC = &lds[2][0];
  short* cD = &lds[3][0];
  short* cE = &lds[4][0];

  STAGE(cA, 0); STAGE(cB, 1); STAGE(cC, 2); STAGE(cD, 3);

#pragma unroll 1
  for (int b = 0; b < 28; ++b) {
    STAGE(cE, b + 4);
    PIPE_WAIT(12);          // drains step b's group (distance-4)
    COMPUTE(cA);
    PIPE_END;
    short* t = cA; cA = cB; cB = cC; cC = cD; cD = cE; cE = t;
  }
  PIPE_WAIT(9); COMPUTE(cA); PIPE_END;   // b=28
  PIPE_WAIT(6); COMPUTE(cB); PIPE_END;   // b=29
  PIPE_WAIT(3); COMPUTE(cC); PIPE_END;   // b=30
  PIPE_WAIT(0); COMPUTE(cD);             // b=31

  {
    const int hQ = ng * 16 + col;
    const float biasq = bq[hQ];
    const float biask = bk[hQ];
    const float biasv = bv[hQ];
#pragma unroll
    for (int r = 0; r < 4; ++r) {
      const int tok = tokbase + mg * 16 + 4 * g + r;
      float fq = accQ[r] + biasq;
      short qh = f2bf(fq);
      q_hi[(size_t)tok * 64 + hQ] = qh;
      q_lo[(size_t)tok * 64 + hQ] = f2bf(fq - bf2f(qh));
      float fk = accK[r] + biask;
      short kh = f2bf(fk);
      k_hi[(size_t)tok * 64 + hQ] = kh;
      k_lo[(size_t)tok * 64 + hQ] = f2bf(fk - bf2f(kh));
      const int bb = tok >> 11;
      const int tl = tok & 2047;
      v_t[((size_t)bb * 64 + hQ) * 2048 + tl] = f2bf(accV[r] + biasv);
    }
  }
#undef STAGE
#undef PIPE_WAIT
#undef PIPE_END
#undef COMPUTE
}

// ============================================================
// Kernel 2: QK^T + softmax-numerator, P materialized.
// grid 256 = (Tpair:64 LPT x b:4), 512 thr = 8 waves. Block covers q-tiles
// t0=2T, t1=2T+1; wave w strides key-subtiles kt = w, w+8, ... <= t.
// Two passes: (1) per-ROW max (per-lane fmax in loop; ONE 2-shfl reduce per
// wave at the end); (2) recompute scores, p = exp2(s - m_row), store
// P[q][key] bf16 tiles (s16x4/lane, fully coalesced). No LDS, no barriers,
// no online rescale. Per-wave partials pm/pl[w][row] for pv's merge.
// b in low bits: each XCD sees ~1 batch -> K (4MB hi+lo) L2-resident.
// ============================================================
__global__ __launch_bounds__(512) void qk_p(
    const short* __restrict__ q_hi, const short* __restrict__ q_lo,
    const short* __restrict__ k_hi, const short* __restrict__ k_lo,
    short* __restrict__ P, float* __restrict__ pm, float* __restrict__ pl) {
  const int tid = threadIdx.x;
  const int lane = tid & 63;
  const int w = tid >> 6;          // 0..7
  const int col = lane & 15;
  const int g = lane >> 4;
  const int T = 63 - (blockIdx.x >> 2);   // LPT: big tiles first
  const int b = blockIdx.x & 3;
  const int t0 = 2 * T, t1 = 2 * T + 1;

  // ---- Q fragments for both tiles (load once, pin against remat) ----
  const short* q0h = q_hi + (size_t)(b * 2048 + t0 * 16 + col) * 64 + g * 8;
  const short* q0l = q_lo + (size_t)(b * 2048 + t0 * 16 + col) * 64 + g * 8;
  s16x8 qh00 = *(const s16x8*)(q0h);
  s16x8 qh01 = *(const s16x8*)(q0h + 32);
  s16x8 ql00 = *(const s16x8*)(q0l);
  s16x8 ql01 = *(const s16x8*)(q0l + 32);
  s16x8 qh10 = *(const s16x8*)(q0h + 16 * 64);
  s16x8 qh11 = *(const s16x8*)(q0h + 16 * 64 + 32);
  s16x8 ql10 = *(const s16x8*)(q0l + 16 * 64);
  s16x8 ql11 = *(const s16x8*)(q0l + 16 * 64 + 32);
  asm volatile("" : "+v"(qh00), "+v"(qh01), "+v"(ql00), "+v"(ql01));
  asm volatile("" : "+v"(qh10), "+v"(qh11), "+v"(ql10), "+v"(ql11));

  // score tile for (K frags, Q frags of one tile), with diagonal mask
#define SCORES(OUT, QH0, QH1, QL0, QL1, TT, KT) do { \
    f32x4 u1_ = {0,0,0,0}, u2_ = {0,0,0,0}; \
    u1_ = mfma32(kh0_, QH0, u1_); u1_ = mfma32(kh1_, QH1, u1_); \
    u2_ = mfma32(kh0_, QL0, u2_); u2_ = mfma32(kh1_, QL1, u2_); \
    u2_ = mfma32(kl0_, QH0, u2_); u2_ = mfma32(kl1_, QH1, u2_); \
    OUT = u1_ + u2_; \
    if ((KT) == (TT)) { \
      _Pragma("unroll") for (int i = 0; i < 4; ++i) \
        if (4 * g + i > col) OUT[i] = -3.0e38f; \
    } \
  } while (0)

  float m0 = -3.0e38f, m1 = -3.0e38f;

  // ---- pass 1: per-lane running max ----
#pragma unroll 1
  for (int kt = w; kt <= t1; kt += 8) {
    const short* krh = k_hi + (size_t)(b * 2048 + kt * 16 + col) * 64 + g * 8;
    const short* krl = k_lo + (size_t)(b * 2048 + kt * 16 + col) * 64 + g * 8;
    s16x8 kh0_ = *(const s16x8*)(krh);
    s16x8 kh1_ = *(const s16x8*)(krh + 32);
    s16x8 kl0_ = *(const s16x8*)(krl);
    s16x8 kl1_ = *(const s16x8*)(krl + 32);
    f32x4 s_;
    SCORES(s_, qh10, qh11, ql10, ql11, t1, kt);
    m1 = fmaxf(m1, fmaxf(fmaxf(s_[0], s_[1]), fmaxf(s_[2], s_[3])));
    if (kt <= t0) {
      SCORES(s_, qh00, qh01, ql00, ql01, t0, kt);
      m0 = fmaxf(m0, fmaxf(fmaxf(s_[0], s_[1]), fmaxf(s_[2], s_[3])));
    }
  }
  // one cross-lane reduce per wave: per-row (q-col) max over all key groups
  m0 = fmaxf(m0, __shfl_xor(m0, 16));
  m0 = fmaxf(m0, __shfl_xor(m0, 32));
  m1 = fmaxf(m1, __shfl_xor(m1, 16));
  m1 = fmaxf(m1, __shfl_xor(m1, 32));

  float lw0 = 0.0f, lw1 = 0.0f;

  // ---- pass 2: recompute (bit-identical), exponentiate, store P ----
#pragma unroll 1
  for (int kt = w; kt <= t1; kt += 8) {
    const short* krh = k_hi + (size_t)(b * 2048 + kt * 16 + col) * 64 + g * 8;
    const short* krl = k_lo + (size_t)(b * 2048 + kt * 16 + col) * 64 + g * 8;
    s16x8 kh0_ = *(const s16x8*)(krh);
    s16x8 kh1_ = *(const s16x8*)(krh + 32);
    s16x8 kl0_ = *(const s16x8*)(krl);
    s16x8 kl1_ = *(const s16x8*)(krl + 32);
    f32x4 s_;
    __builtin_amdgcn_s_setprio(1);
    SCORES(s_, qh10, qh11, ql10, ql11, t1, kt);
    __builtin_amdgcn_s_setprio(0);
    {
      const float p0 = __builtin_amdgcn_exp2f((s_[0] - m1) * LOG2E);
      const float p1 = __builtin_amdgcn_exp2f((s_[1] - m1) * LOG2E);
      const float p2 = __builtin_amdgcn_exp2f((s_[2] - m1) * LOG2E);
      const float p3 = __builtin_amdgcn_exp2f((s_[3] - m1) * LOG2E);
      lw1 += p0 + p1 + p2 + p3;
      s16x4 pb;
      pb[0] = f2bf(p0); pb[1] = f2bf(p1); pb[2] = f2bf(p2); pb[3] = f2bf(p3);
      *(s16x4*)(P + ((size_t)((b * 128 + t1) * 128 + kt)) * 256 + col * 16 + 4 * g) = pb;
    }
    if (kt <= t0) {
      __builtin_amdgcn_s_setprio(1);
      SCORES(s_, qh00, qh01, ql00, ql01, t0, kt);
      __builtin_amdgcn_s_setprio(0);
      const float p0 = __builtin_amdgcn_exp2f((s_[0] - m0) * LOG2E);
      const float p1 = __builtin_amdgcn_exp2f((s_[1] - m0) * LOG2E);
      const float p2 = __builtin_amdgcn_exp2f((s_[2] - m0) * LOG2E);
      const float p3 = __builtin_amdgcn_exp2f((s_[3] - m0) * LOG2E);
      lw0 += p0 + p1 + p2 + p3;
      s16x4 pb;
      pb[0] = f2bf(p0); pb[1] = f2bf(p1); pb[2] = f2bf(p2); pb[3] = f2bf(p3);
      *(s16x4*)(P + ((size_t)((b * 128 + t0) * 128 + kt)) * 256 + col * 16 + 4 * g) = pb;
    }
  }
  lw0 += __shfl_xor(lw0, 16); lw0 += __shfl_xor(lw0, 32);
  lw1 += __shfl_xor(lw1, 16); lw1 += __shfl_xor(lw1, 32);

  if (g == 0) {   // per-(wave, row) partials; ALWAYS written (empty waves too)
    pm[w * 8192 + b * 2048 + t0 * 16 + col] = m0;
    pl[w * 8192 + b * 2048 + t0 * 16 + col] = lw0;
    pm[w * 8192 + b * 2048 + t1 * 16 + col] = m1;
    pl[w * 8192 + b * 2048 + t1 * 16 + col] = lw1;
  }
#undef SCORES
}

// ============================================================
// Kernel 3: PV + merge. Same grid/wave mapping as qk_p (wave w consumes
// exactly the P tiles it wrote -> per-(wave,tile) scale is consistent).
// Loop body: 1 P-frag load + 4 V^T frags + 4 mfma16 — no cross-lane ops,
// no barriers in the loop. End: per-tile LDS merge over the 8 waves
// (weights exp2(m_w - M), l from pl), writes out directly.
// ============================================================
__global__ __launch_bounds__(512) void pv(
    const short* __restrict__ P, const short* __restrict__ v_t,
    const float* __restrict__ pm, const float* __restrict__ pl,
    float* __restrict__ out) {
  const int tid = threadIdx.x;
  const int lane = tid & 63;
  const int w = tid >> 6;          // 0..7
  const int col = lane & 15;
  const int g = lane >> 4;
  const int T = 63 - (blockIdx.x >> 2);
  const int b = blockIdx.x & 3;
  const int t0 = 2 * T, t1 = 2 * T + 1;

  __shared__ float ldsO[8 * 64 * 17];   // 34.8 KB, reused for t0 then t1

  f32x4 o00 = {0,0,0,0}, o01 = {0,0,0,0}, o02 = {0,0,0,0}, o03 = {0,0,0,0};
  f32x4 o10 = {0,0,0,0}, o11 = {0,0,0,0}, o12 = {0,0,0,0}, o13 = {0,0,0,0};

  const short* vbase = v_t + ((size_t)b * 64 + col) * 2048 + 4 * g;

#pragma unroll 1
  for (int kt = w; kt <= t1; kt += 8) {
    const short* vr = vbase + 16 * kt;
    s16x4 v0 = *(const s16x4*)(vr);
    s16x4 v1 = *(const s16x4*)(vr + 16 * 2048);
    s16x4 v2 = *(const s16x4*)(vr + 32 * 2048);
    s16x4 v3 = *(const s16x4*)(vr + 48 * 2048);
    s16x4 pb1 = *(const s16x4*)(P + ((size_t)((b * 128 + t1) * 128 + kt)) * 256 + col * 16 + 4 * g);
    __builtin_amdgcn_s_setprio(1);
    o10 = mfma16(v0, pb1, o10);
    o11 = mfma16(v1, pb1, o11);
    o12 = mfma16(v2, pb1, o12);
    o13 = mfma16(v3, pb1, o13);
    __builtin_amdgcn_s_setprio(0);
    if (kt <= t0) {
      s16x4 pb0 = *(const s16x4*)(P + ((size_t)((b * 128 + t0) * 128 + kt)) * 256 + col * 16 + 4 * g);
      __builtin_amdgcn_s_setprio(1);
      o00 = mfma16(v0, pb0, o00);
      o01 = mfma16(v1, pb0, o01);
      o02 = mfma16(v2, pb0, o02);
      o03 = mfma16(v3, pb0, o03);
      __builtin_amdgcn_s_setprio(0);
    }
  }

  // merge one tile: waves deposit O^T frags; 512 thr combine with pm/pl weights
#define MERGE(TT, O0, O1, O2, O3) do { \
    _Pragma("unroll") \
    for (int r = 0; r < 4; ++r) { \
      ldsO[(w * 64 +  0 + 4 * g + r) * 17 + col] = O0[r]; \
      ldsO[(w * 64 + 16 + 4 * g + r) * 17 + col] = O1[r]; \
      ldsO[(w * 64 + 32 + 4 * g + r) * 17 + col] = O2[r]; \
      ldsO[(w * 64 + 48 + 4 * g + r) * 17 + col] = O3[r]; \
    } \
    __syncthreads(); \
    { \
      const int q = tid >> 5;          /* 0..15 */ \
      const int h0 = tid & 31;         /* 0..31 */ \
      const int row = b * 2048 + (TT) * 16 + q; \
      float mw[8], lw[8]; \
      _Pragma("unroll") \
      for (int u = 0; u < 8; ++u) { mw[u] = pm[u * 8192 + row]; lw[u] = pl[u * 8192 + row]; } \
      float M = mw[0]; \
      _Pragma("unroll") for (int u = 1; u < 8; ++u) M = fmaxf(M, mw[u]); \
      float ew[8]; float L = 0.0f; \
      _Pragma("unroll") \
      for (int u = 0; u < 8; ++u) { \
        ew[u] = __builtin_amdgcn_exp2f((mw[u] - M) * LOG2E); \
        L += ew[u] * lw[u]; \
      } \
      const float invL = 1.0f / L; \
      _Pragma("unroll") \
      for (int e = 0; e < 2; ++e) { \
        const int h = h0 + 32 * e; \
        float acc = 0.0f; \
        _Pragma("unroll") \
        for (int u = 0; u < 8; ++u) acc += ew[u] * ldsO[(u * 64 + h) * 17 + q]; \
        out[(size_t)row * 64 + h] = acc * invL; \
      } \
    } \
    __syncthreads(); \
  } while (0)

  MERGE(t0, o00, o01, o02, o03);
  MERGE(t1, o10, o11, o12, o13);
#undef MERGE
}

// ============================================================
extern "C" void kernel_launch(void* const* d_in, const int* in_sizes, int n_in,
                              void* d_out, int out_size, void* d_ws, size_t ws_size,
                              hipStream_t stream) {
  const float* x  = (const float*)d_in[0];
  const float* Wq = (const float*)d_in[1];
  const float* bq = (const float*)d_in[2];
  const float* Wk = (const float*)d_in[3];
  const float* bk = (const float*)d_in[4];
  const float* Wv = (const float*)d_in[5];
  const float* bv = (const float*)d_in[6];
  float* out = (float*)d_out;

  char* ws = (char*)d_ws;
  short* wt_hi = (short*)(ws);                       // 393216 B
  short* wt_lo = (short*)(ws + 393216);
  short* q_hi  = (short*)(ws + 786432);              // 1 MiB each
  short* q_lo  = (short*)(ws + 786432 + 1048576);
  short* k_hi  = (short*)(ws + 786432 + 2 * 1048576);
  short* k_lo  = (short*)(ws + 786432 + 3 * 1048576);
  short* v_t   = (short*)(ws + 786432 + 4 * 1048576); // end 6,029,312
  short* Pbuf  = (short*)(ws + 6029312);              // 4*128*128*256*2 = 33,554,432
  float* pm    = (float*)(ws + 39583744);             // 8*8192*4 = 262,144
  float* pl    = (float*)(ws + 39845888);             // 262,144 -> end 40,108,032

  hipLaunchKernelGGL(prep_w, dim3(768), dim3(256), 0, stream, Wq, Wk, Wv, wt_hi, wt_lo);
  hipLaunchKernelGGL(proj_qkv, dim3(256), dim3(512), 0, stream,
                     x, wt_hi, wt_lo, bq, bk, bv, q_hi, q_lo, k_hi, k_lo, v_t);
  hipLaunchKernelGGL(qk_p, dim3(256), dim3(512), 0, stream,
                     q_hi, q_lo, k_hi, k_lo, Pbuf, pm, pl);
  hipLaunchKernelGGL(pv, dim3(256), dim3(512), 0, stream,
                     Pbuf, v_t, pm, pl, out);
}